// Round 15
// baseline (206.409 us; speedup 1.0000x reference)
//
#include <hip/hip_runtime.h>
#include <hip/hip_bf16.h>
#include <string.h>

// CrossOp via bf16 MFMA (32x32x16) implicit-GEMM, 2-row h-band blocks.
// Block = (b, hb): TWO output rows x 128 px x 64 co. Grid 256 = 1 block/CU.
// 1024 threads = 16 waves: wave w -> co-half (w&1)*32, hh=(w>>1)&1, wq=w>>2.
// Round-13 structure + STORE-LATE: iteration s's 16 NT stores are issued at
// the START of iteration s+1 (after the staging loads, before MFMA) from a
// double-buffered accumulator (accA/accB, even/odd unroll for static roles).
// This keeps the HBM write queue fed across the MFMA+barrier phases instead
// of bursting at the iteration end (1 block/CU has no other block to fill
// the gap). Pipeline: write-then-reissue depth-2, counted vmcnt, NT stores
// never drained in-loop, lgkm-only barrier.
// LDS: y dbuf 2 x [4 rows][130 cols][16ci pad->24] + static x tile = 74.9 KB.

typedef __attribute__((ext_vector_type(8))) short short8;
typedef __attribute__((ext_vector_type(16))) float f32x16;
typedef __attribute__((ext_vector_type(4))) unsigned int u32x4;

#define NEG_SLOPE 0.01f

constexpr int CIP    = 24;             // shorts per (row,col) ci slab (48 B)
constexpr int COLS   = 130;            // 128 + 2 halo (halo cols stay zero)
constexpr int ROWP   = COLS * CIP;     // 3120 shorts
constexpr int TILESH = 4 * ROWP;       // 12480 shorts = 24.96 KB per tile

__device__ __forceinline__ short to_bf16s(float f) {
    unsigned u = __builtin_bit_cast(unsigned, f);
    u += 0x7fffu + ((u >> 16) & 1u);   // RNE
    return (short)(u >> 16);
}

__device__ __forceinline__ unsigned pack2(float a, float b) {
    __hip_bfloat162 t = __float22bfloat162_rn(float2{a, b});   // v_cvt_pk_bf16_f32
    unsigned u;
    memcpy(&u, &t, sizeof(u));
    return u;
}

__global__ __launch_bounds__(1024, 4)
void crossop_v6(const float* __restrict__ xp, const float* __restrict__ yp,
                const float* __restrict__ wp, const float* __restrict__ bp,
                float* __restrict__ out)
{
    __shared__ __align__(16) short st[3][TILESH];   // [0],[1]=y dbuf, [2]=x static

    const int bid     = blockIdx.x;                     // 0..255
    const int logical = ((bid & 7) << 5) | (bid >> 3);  // XCD-chunked swizzle
    const int b       = logical >> 6;                   // 0..3
    const int hb      = logical & 63;                   // 2-row band index

    const int tid  = threadIdx.x;
    const int lane = tid & 63;
    const int wid  = tid >> 6;             // 0..15
    const int l31  = lane & 31;
    const int hi   = lane >> 5;            // k-half / +4 co rows
    const int co0w = (wid & 1) << 5;       // wave's co base (0 or 32)
    const int pxg  = wid >> 1;             // 0..7
    const int hh   = pxg & 1;              // which of the 2 output rows
    const int wq   = pxg >> 1;             // w-quad (0..3), 32 px

    float* ntgt  = out;
    float* inter = out + (size_t)4 * 64 * 16384;
    const float* ybase = yp + (size_t)b * 32 * 16 * 16384;

    // ---------------- zero LDS once (halo cols / OOB rows stay 0) ---------
    {
        u32x4 zz = {0, 0, 0, 0};
        u32x4* z = (u32x4*)&st[0][0];
        for (int i = tid; i < (3 * TILESH * 2) / 16; i += 1024) z[i] = zz;
    }

    // ---------------- staging: 1024 threads, 8 values each -----------------
    const int  wv   = tid & 127;           // input col / tile col wv+1
    const int  ch   = tid >> 7;            // 0..7
    const int  rr   = ch >> 1;             // tile row 0..3 (input row hb*2-1+rr)
    const int  cih  = ch & 1;              // ci half
    const int  hin  = hb * 2 - 1 + rr;
    const bool sval = (unsigned)hin < 128u;
    float sr[8];

#define STAGE_ISSUE(SRC) do {                                                 \
    const float* p = (SRC) + (ptrdiff_t)(cih * 8) * 16384                     \
                            + (ptrdiff_t)hin * 128 + wv;                      \
    _Pragma("unroll")                                                         \
    for (int c = 0; c < 8; ++c)                                               \
        sr[c] = sval ? p[(ptrdiff_t)c * 16384] : 0.f;                         \
    } while (0)

#define STAGE_WRITE(BUF) do { if (sval) {                                     \
    u32x4 vv;                                                                 \
    _Pragma("unroll")                                                         \
    for (int c2 = 0; c2 < 4; ++c2)                                            \
        vv[c2] = pack2(sr[2 * c2], sr[2 * c2 + 1]);                           \
    *(u32x4*)&(BUF)[rr * ROWP + (wv + 1) * CIP + cih * 8] = vv;               \
    } } while (0)

    // ---------------- persistent wy fragments (9 x short8 = 36 VGPR) ------
    short8 wy[9];
    #pragma unroll
    for (int sh = 0; sh < 9; ++sh) {
        #pragma unroll
        for (int j = 0; j < 8; ++j) {
            int ci = hi * 8 + j;           // k = (lane>>5)*8 + j within k-step
            wy[sh][j] = to_bf16s(wp[((co0w + l31) * 32 + 16 + ci) * 9 + sh]);
        }
    }

    // per-lane B column base; output px reads tile rows hh..hh+2
    const int cb = (wq * 32 + l31) * CIP + hi * 8;

    // ---------------- prologue: x -> st[2]; ox = conv_x + bias -------------
    STAGE_ISSUE(xp + (size_t)b * 16 * 16384);
    STAGE_WRITE(st[2]);
    __syncthreads();

    f32x16 ox;
    #pragma unroll
    for (int r = 0; r < 16; ++r)
        ox[r] = bp[co0w + (r & 3) + 8 * (r >> 2) + 4 * hi];
    {
        const short* sb = st[2];
        #pragma unroll
        for (int sh = 0; sh < 9; ++sh) {
            short8 ax;
            #pragma unroll
            for (int j = 0; j < 8; ++j) {
                int ci = hi * 8 + j;
                ax[j] = to_bf16s(wp[((co0w + l31) * 32 + ci) * 9 + sh]);
            }
            const int off = (sh / 3 + hh) * ROWP + (sh % 3) * CIP;
            ox = __builtin_amdgcn_mfma_f32_32x32x16_bf16(ax, *(const short8*)&sb[cb + off], ox, 0, 0, 0);
        }
    }

    // y0 -> st[1] (full-latency, prologue only), then prefetch y1 -> sr
    STAGE_ISSUE(ybase + (size_t)0 * 16 * 16384);
    STAGE_WRITE(st[1]);
    STAGE_ISSUE(ybase + (size_t)1 * 16 * 16384);
    __syncthreads();

    // ---------------- s-loop with store-late acc double-buffer -------------
    f32x16 ms;
    #pragma unroll
    for (int r = 0; r < 16; ++r) ms[r] = 0.f;

    f32x16 accA, accB;

#define MFMA_PHASE(S, ACC) do {                                               \
    const short* sb = st[((S) + 1) & 1];                                      \
    ACC = ox;                                                                 \
    _Pragma("unroll")                                                         \
    for (int sh = 0; sh < 9; ++sh) {                                          \
        const int off = (sh / 3 + hh) * ROWP + (sh % 3) * CIP;                \
        ACC = __builtin_amdgcn_mfma_f32_32x32x16_bf16(                        \
            wy[sh], *(const short8*)&sb[cb + off], ACC, 0, 0, 0);             \
    } } while (0)

#define STORE_PHASE(S, ACC) do {                                              \
    float* p0 = inter + ((size_t)(b * 32 + (S)) * 64 + co0w + 4 * hi) * 16384 \
              + (size_t)(hb * 2 + hh) * 128 + wq * 32 + l31;                  \
    _Pragma("unroll")                                                         \
    for (int r = 0; r < 16; ++r) {                                            \
        float v = ACC[r];                                                     \
        v = v >= 0.f ? v : NEG_SLOPE * v;                                     \
        __builtin_nontemporal_store(v, p0 + (ptrdiff_t)((r & 3) + 8 * (r >> 2)) * 16384); \
        ms[r] += v;                                                           \
    } } while (0)

#define BARRIER() do {                                                        \
    asm volatile("s_waitcnt lgkmcnt(0)" ::: "memory");                        \
    __builtin_amdgcn_s_barrier();                                             \
    asm volatile("" ::: "memory");                                            \
} while (0)

    // peeled s = 0: no stores yet
    STAGE_WRITE(st[0]);                                  // y1
    STAGE_ISSUE(ybase + (size_t)2 * 16 * 16384);         // y2 -> sr
    MFMA_PHASE(0, accA);
    BARRIER();

    // s = 1..31: stores of acc(s-1) issued EARLY (before MFMA of s)
    for (int s = 1; s < 32; s += 2) {
        {   // odd s: compute into accB, store accA (= acc(s-1))
            if (s + 1 < 32) STAGE_WRITE(st[s & 1]);                       // y(s+1)
            if (s + 2 < 32) STAGE_ISSUE(ybase + (size_t)(s + 2) * 16 * 16384);
            STORE_PHASE(s - 1, accA);
            MFMA_PHASE(s, accB);
            BARRIER();
        }
        if (s + 1 < 32) {   // even s+1: compute into accA, store accB
            const int t = s + 1;
            if (t + 1 < 32) STAGE_WRITE(st[t & 1]);                       // y(t+1)
            if (t + 2 < 32) STAGE_ISSUE(ybase + (size_t)(t + 2) * 16 * 16384);
            STORE_PHASE(t - 1, accB);
            MFMA_PHASE(t, accA);
            BARRIER();
        }
    }

    // epilogue: last computed is s=31 in accB (31 odd -> accB)
    STORE_PHASE(31, accB);

    // ---------------- mean over Sy ----------------------------------------
    {
        float* p0 = ntgt + ((size_t)b * 64 + co0w + 4 * hi) * 16384
                  + (size_t)(hb * 2 + hh) * 128 + wq * 32 + l31;
        #pragma unroll
        for (int r = 0; r < 16; ++r)
            __builtin_nontemporal_store(ms[r] * 0.03125f,
                                        p0 + (ptrdiff_t)((r & 3) + 8 * (r >> 2)) * 16384);
    }
#undef MFMA_PHASE
#undef STORE_PHASE
#undef BARRIER
#undef STAGE_ISSUE
#undef STAGE_WRITE
}

extern "C" void kernel_launch(void* const* d_in, const int* in_sizes, int n_in,
                              void* d_out, int out_size, void* d_ws, size_t ws_size,
                              hipStream_t stream) {
    const float* x    = (const float*)d_in[0];
    const float* y    = (const float*)d_in[1];
    const float* wgt  = (const float*)d_in[2];
    const float* bias = (const float*)d_in[3];
    float* out = (float*)d_out;

    crossop_v6<<<256, 1024, 0, stream>>>(x, y, wgt, bias, out);
}

// Round 16
// 142.219 us; speedup vs baseline: 1.4513x; 1.4513x over previous
//
#include <hip/hip_runtime.h>
#include <hip/hip_bf16.h>
#include <string.h>

// CrossOp via bf16 MFMA (32x32x16) implicit-GEMM, 2-row h-band blocks.
// ===== ROUND-13 CHAMPION (141.9 us), reverted after R14/R15 regressions =====
// Block = (b, hb): TWO output rows (h = hb*2, hb*2+1) x 128 px x 64 co.
// Grid 256 = 1 block/CU. 1024 threads = 16 waves:
//   wave w: co-half (w&1)*32, hh = (w>>1)&1, w-quad = w>>2 (32 px).
// Per iteration the block writes 2h x 128w x 64co: per co-plane 1 KB
// CONTIGUOUS and simultaneous -> best measured DRAM-page efficiency.
// Pipeline: write-then-reissue depth-2, counted vmcnt (NT stores never
// drained in-loop), lgkm-only barrier.
// LDS: y dbuf 2 x [4 rows][130 cols][16ci pad->24] + static x tile = 74.9 KB.

typedef __attribute__((ext_vector_type(8))) short short8;
typedef __attribute__((ext_vector_type(16))) float f32x16;
typedef __attribute__((ext_vector_type(4))) unsigned int u32x4;

#define NEG_SLOPE 0.01f

constexpr int CIP    = 24;             // shorts per (row,col) ci slab (48 B)
constexpr int COLS   = 130;            // 128 + 2 halo (halo cols stay zero)
constexpr int ROWP   = COLS * CIP;     // 3120 shorts
constexpr int TILESH = 4 * ROWP;       // 12480 shorts = 24.96 KB per tile

__device__ __forceinline__ short to_bf16s(float f) {
    unsigned u = __builtin_bit_cast(unsigned, f);
    u += 0x7fffu + ((u >> 16) & 1u);   // RNE
    return (short)(u >> 16);
}

__device__ __forceinline__ unsigned pack2(float a, float b) {
    __hip_bfloat162 t = __float22bfloat162_rn(float2{a, b});   // v_cvt_pk_bf16_f32
    unsigned u;
    memcpy(&u, &t, sizeof(u));
    return u;
}

__global__ __launch_bounds__(1024, 4)
void crossop_v4(const float* __restrict__ xp, const float* __restrict__ yp,
                const float* __restrict__ wp, const float* __restrict__ bp,
                float* __restrict__ out)
{
    __shared__ __align__(16) short st[3][TILESH];   // [0],[1]=y dbuf, [2]=x static

    const int bid     = blockIdx.x;                     // 0..255
    const int logical = ((bid & 7) << 5) | (bid >> 3);  // XCD-chunked swizzle
    const int b       = logical >> 6;                   // 0..3
    const int hb      = logical & 63;                   // 2-row band index

    const int tid  = threadIdx.x;
    const int lane = tid & 63;
    const int wid  = tid >> 6;             // 0..15
    const int l31  = lane & 31;
    const int hi   = lane >> 5;            // k-half / +4 co rows
    const int co0w = (wid & 1) << 5;       // wave's co base (0 or 32)
    const int pxg  = wid >> 1;             // 0..7
    const int hh   = pxg & 1;              // which of the 2 output rows
    const int wq   = pxg >> 1;             // w-quad (0..3), 32 px

    float* ntgt  = out;
    float* inter = out + (size_t)4 * 64 * 16384;
    const float* ybase = yp + (size_t)b * 32 * 16 * 16384;

    // ---------------- zero LDS once (halo cols / OOB rows stay 0) ---------
    {
        u32x4 zz = {0, 0, 0, 0};
        u32x4* z = (u32x4*)&st[0][0];
        for (int i = tid; i < (3 * TILESH * 2) / 16; i += 1024) z[i] = zz;
    }

    // ---------------- staging: 1024 threads, 8 values each -----------------
    const int  wv   = tid & 127;           // input col / tile col wv+1
    const int  ch   = tid >> 7;            // 0..7
    const int  rr   = ch >> 1;             // tile row 0..3 (input row hb*2-1+rr)
    const int  cih  = ch & 1;              // ci half
    const int  hin  = hb * 2 - 1 + rr;
    const bool sval = (unsigned)hin < 128u;
    float sr[8];

#define STAGE_ISSUE(SRC) do {                                                 \
    const float* p = (SRC) + (ptrdiff_t)(cih * 8) * 16384                     \
                            + (ptrdiff_t)hin * 128 + wv;                      \
    _Pragma("unroll")                                                         \
    for (int c = 0; c < 8; ++c)                                               \
        sr[c] = sval ? p[(ptrdiff_t)c * 16384] : 0.f;                         \
    } while (0)

#define STAGE_WRITE(BUF) do { if (sval) {                                     \
    u32x4 vv;                                                                 \
    _Pragma("unroll")                                                         \
    for (int c2 = 0; c2 < 4; ++c2)                                            \
        vv[c2] = pack2(sr[2 * c2], sr[2 * c2 + 1]);                           \
    *(u32x4*)&(BUF)[rr * ROWP + (wv + 1) * CIP + cih * 8] = vv;               \
    } } while (0)

    // ---------------- persistent wy fragments (9 x short8 = 36 VGPR) ------
    short8 wy[9];
    #pragma unroll
    for (int sh = 0; sh < 9; ++sh) {
        #pragma unroll
        for (int j = 0; j < 8; ++j) {
            int ci = hi * 8 + j;           // k = (lane>>5)*8 + j within k-step
            wy[sh][j] = to_bf16s(wp[((co0w + l31) * 32 + 16 + ci) * 9 + sh]);
        }
    }

    // per-lane B column base; output px p reads tile cols p..p+2, rows hh+kh
    const int cb = (wq * 32 + l31) * CIP + hi * 8;

    // ---------------- prologue: x -> st[2]; ox = conv_x + bias -------------
    STAGE_ISSUE(xp + (size_t)b * 16 * 16384);
    STAGE_WRITE(st[2]);
    __syncthreads();

    f32x16 ox;
    #pragma unroll
    for (int r = 0; r < 16; ++r)
        ox[r] = bp[co0w + (r & 3) + 8 * (r >> 2) + 4 * hi];
    {
        const short* sb = st[2];
        #pragma unroll
        for (int sh = 0; sh < 9; ++sh) {
            short8 ax;
            #pragma unroll
            for (int j = 0; j < 8; ++j) {
                int ci = hi * 8 + j;
                ax[j] = to_bf16s(wp[((co0w + l31) * 32 + ci) * 9 + sh]);
            }
            const int off = (sh / 3 + hh) * ROWP + (sh % 3) * CIP;
            ox = __builtin_amdgcn_mfma_f32_32x32x16_bf16(ax, *(const short8*)&sb[cb + off], ox, 0, 0, 0);
        }
    }

    // y0 -> st[1] (full-latency, prologue only), then prefetch y1 -> sr
    STAGE_ISSUE(ybase + (size_t)0 * 16 * 16384);
    STAGE_WRITE(st[1]);
    STAGE_ISSUE(ybase + (size_t)1 * 16 * 16384);
    __syncthreads();

    // ---------------- s-loop: write-then-reissue depth-2 pipeline ----------
    f32x16 ms;
    #pragma unroll
    for (int r = 0; r < 16; ++r) ms[r] = 0.f;

    for (int s = 0; s < 32; ++s) {
        // 1) ds_write sr (= y(s+1)): counted vmcnt, NT stores stay in flight
        if (s + 1 < 32) STAGE_WRITE(st[s & 1]);

        // 2) reissue the SAME sr registers with y(s+2) loads
        if (s + 2 < 32) STAGE_ISSUE(ybase + (size_t)(s + 2) * 16 * 16384);

        // 3) MFMA phase on y_s (st[(s+1)&1])
        const short* sb = st[(s + 1) & 1];
        f32x16 acc = ox;
        #pragma unroll
        for (int sh = 0; sh < 9; ++sh) {
            const int off = (sh / 3 + hh) * ROWP + (sh % 3) * CIP;
            acc = __builtin_amdgcn_mfma_f32_32x32x16_bf16(wy[sh], *(const short8*)&sb[cb + off], acc, 0, 0, 0);
        }

        // 4) leaky + NT stores: block writes 1 KB contiguous per co-plane
        {
            float* p0 = inter + ((size_t)(b * 32 + s) * 64 + co0w + 4 * hi) * 16384
                      + (size_t)(hb * 2 + hh) * 128 + wq * 32 + l31;
            #pragma unroll
            for (int r = 0; r < 16; ++r) {
                float v = acc[r];
                v = v >= 0.f ? v : NEG_SLOPE * v;
                __builtin_nontemporal_store(v, p0 + (ptrdiff_t)((r & 3) + 8 * (r >> 2)) * 16384);
                ms[r] += v;
            }
        }

        // 5) LDS-only barrier
        asm volatile("s_waitcnt lgkmcnt(0)" ::: "memory");
        __builtin_amdgcn_s_barrier();
        asm volatile("" ::: "memory");
    }

    // ---------------- mean over Sy ----------------------------------------
    {
        float* p0 = ntgt + ((size_t)b * 64 + co0w + 4 * hi) * 16384
                  + (size_t)(hb * 2 + hh) * 128 + wq * 32 + l31;
        #pragma unroll
        for (int r = 0; r < 16; ++r)
            __builtin_nontemporal_store(ms[r] * 0.03125f,
                                        p0 + (ptrdiff_t)((r & 3) + 8 * (r >> 2)) * 16384);
    }
#undef STAGE_ISSUE
#undef STAGE_WRITE
}

extern "C" void kernel_launch(void* const* d_in, const int* in_sizes, int n_in,
                              void* d_out, int out_size, void* d_ws, size_t ws_size,
                              hipStream_t stream) {
    const float* x    = (const float*)d_in[0];
    const float* y    = (const float*)d_in[1];
    const float* wgt  = (const float*)d_in[2];
    const float* bias = (const float*)d_in[3];
    float* out = (float*)d_out;

    crossop_v4<<<256, 1024, 0, stream>>>(x, y, wgt, bias, out);
}